// Round 10
// baseline (155.136 us; speedup 1.0000x reference)
//
#include <hip/hip_runtime.h>
#include <hip/hip_bf16.h>
#include <math.h>

// SpikingNeuralNetwork: 3 chained bf16-MFMA GEMMs + elementwise epilogues.
// N = 2048. Round 10: 32 waves/CU WITH double-buffering — split-K=4, BK=32
// dbuf (32 KB LDS/block), 128x128 tile, 8 waves, __launch_bounds__(512,8)
// forcing VGPR<=64 so 4 blocks co-reside per CU. Launch merges: conv-W2 in
// combine1, conv-W3 in combine2, stdp as grid-z slice of GEMM2 (overlapped).

#define NN 2048
#define BK 32
#define KSL (NN / 4)        // 512 per split
#define KTS (KSL / BK)      // 16 K-tiles per split
#define NT (NN / 128)       // 16 tiles per dim

typedef __attribute__((ext_vector_type(8))) short bf16x8;
typedef __attribute__((ext_vector_type(4))) float f32x4;
typedef __attribute__((ext_vector_type(4))) short s16x4;

__device__ __forceinline__ short f2bf(float f) {
    union { float f; unsigned u; } a; a.f = f;
    unsigned r = a.u + 0x7FFFu + ((a.u >> 16) & 1u);   // RNE
    return (short)(r >> 16);
}

__device__ __forceinline__ float bf2f(short s) {
    union { unsigned u; float f; } a;
    a.u = ((unsigned)(unsigned short)s) << 16;
    return a.f;
}

__device__ __forceinline__ void gload16(const short* g, short* l) {
    __builtin_amdgcn_global_load_lds(
        (const __attribute__((address_space(1))) unsigned int*)g,
        (__attribute__((address_space(3))) unsigned int*)l, 16, 0, 0);
}

__device__ __forceinline__ float sigmoidf_(float x) {
    return 1.0f / (1.0f + expf(-x));
}

// ---------------- f32 -> bf16 conversion helpers ----------------
__device__ __forceinline__ void conv_item(const float* __restrict__ src,
                                          short* __restrict__ dst, int i) {
    float4 v = reinterpret_cast<const float4*>(src)[i];
    s16x4 o;
    o.x = f2bf(v.x); o.y = f2bf(v.y); o.z = f2bf(v.z); o.w = f2bf(v.w);
    reinterpret_cast<s16x4*>(dst)[i] = o;
}

__global__ void conv2_kernel(const float* __restrict__ s0, const float* __restrict__ s1,
                             short* __restrict__ d0, short* __restrict__ d1,
                             int* __restrict__ flags)
{
    int i = blockIdx.x * blockDim.x + threadIdx.x;   // over NN*NN/4
    if (blockIdx.y == 0) {
        conv_item(s0, d0, i);
        if (blockIdx.x < NN / 256)
            flags[blockIdx.x * blockDim.x + threadIdx.x] = 0;
    } else {
        conv_item(s1, d1, i);
    }
}

// ---------------- split-K=4 GEMM body ----------------
// C_z = A[:, z*512 +: 512] @ B^T slice. 128x128 tile, 8 waves (2x4) of 64x32,
// BK=32 double-buffered (32 KB LDS), XOR-swizzled. 1024 blocks -> 4/CU.
__device__ __forceinline__ void gemm_body(
    const short* __restrict__ A, const short* __restrict__ B,
    short* __restrict__ P, short* AsBase, short* BsBase)
{
    const int tid  = threadIdx.x;
    const int lane = tid & 63;
    const int wid  = tid >> 6;          // 0..7
    const int row0 = blockIdx.y * 128;
    const int col0 = blockIdx.x * 128;
    const int kbase = blockIdx.z * KSL;
    const int wm   = (wid >> 2) * 64;   // wave sub-tile origin in M (0/64)
    const int wn   = (wid & 3) * 32;    // in N (0/32/64/96)
    const int lrow = lane & 15;
    const int lk16 = (lane >> 4) << 3;  // 0/8/16/24

    f32x4 acc[4][2] = {};

    // Per-thread stage: exactly 1 A-chunk + 1 B-chunk (16 B each) per K-tile.
    // LDS dest linear (global_load_lds requirement); global source inverse-
    // swizzled: LDS chunk q of row r holds global k-chunk q^(r&3) (rule #21).
    const int rS   = tid >> 2;                         // row in tile
    const int ksrc = ((tid & 3) ^ (rS & 3)) << 3;      // swizzled k (bf16 elems)
    const int voffA = (row0 + rS) * NN + kbase + ksrc; // loop-invariant
    const int voffB = (col0 + rS) * NN + kbase + ksrc;
    short* ldsA = AsBase + tid * 8;                    // + buf*128*BK
    short* ldsB = BsBase + tid * 8;

    auto stage = [&](int buf, int k0) {
        gload16(A + voffA + k0, ldsA + buf * (128 * BK));
        gload16(B + voffB + k0, ldsB + buf * (128 * BK));
    };

    auto compute = [&](int buf) {
        const short* as = AsBase + buf * (128 * BK);
        const short* bs = BsBase + buf * (128 * BK);
        bf16x8 af[4], bfv[2];
#pragma unroll
        for (int i = 0; i < 4; ++i) {
            const int row = wm + i * 16 + lrow;
            const int ke  = lk16 ^ ((row & 3) << 3);
            af[i] = *reinterpret_cast<const bf16x8*>(&as[row * BK + ke]);
        }
#pragma unroll
        for (int j = 0; j < 2; ++j) {
            const int row = wn + j * 16 + lrow;
            const int ke  = lk16 ^ ((row & 3) << 3);
            bfv[j] = *reinterpret_cast<const bf16x8*>(&bs[row * BK + ke]);
        }
#pragma unroll
        for (int i = 0; i < 4; ++i)
#pragma unroll
            for (int j = 0; j < 2; ++j)
                acc[i][j] = __builtin_amdgcn_mfma_f32_16x16x32_bf16(
                    af[i], bfv[j], acc[i][j], 0, 0, 0);
    };

    // 2-phase pipeline: STAGE(next) before compute(cur); one vmcnt(0)+barrier
    // per iteration (__syncthreads). 4 blocks/CU fill each other's stalls.
    stage(0, 0);
    __syncthreads();
    int cur = 0;
    for (int t = 0; t < KTS - 1; ++t) {
        stage(cur ^ 1, (t + 1) * BK);
        compute(cur);
        __syncthreads();
        cur ^= 1;
    }
    compute(cur);

    // write bf16 partial — C/D layout: col = lane&15, row = (lane>>4)*4 + reg
    short* outp = P + (size_t)blockIdx.z * NN * NN;
#pragma unroll
    for (int i = 0; i < 4; ++i) {
#pragma unroll
        for (int j = 0; j < 2; ++j) {
            const int gcol = col0 + wn + j * 16 + lrow;
#pragma unroll
            for (int r = 0; r < 4; ++r) {
                const int grow = row0 + wm + i * 16 + ((lane >> 4) << 2) + r;
                outp[(size_t)grow * NN + gcol] = f2bf(acc[i][j][r]);
            }
        }
    }
}

__global__ __launch_bounds__(512, 8) void gemm_partial(
    const short* __restrict__ A, const short* __restrict__ B,
    short* __restrict__ P)
{
    __shared__ short As[2 * 128 * BK] __attribute__((aligned(16)));
    __shared__ short Bs[2 * 128 * BK] __attribute__((aligned(16)));
    gemm_body(A, B, P, As, Bs);
}

// GEMM2 + STDP fused dispatch: grid (16,16,5); z==4 blocks run STDP (overlaps
// the GEMM since STDP only needs flags, finalized by combine1).
__global__ __launch_bounds__(512, 8) void gemm_stdp(
    const short* __restrict__ A, const short* __restrict__ B,
    short* __restrict__ P,
    const float* __restrict__ w, const float* __restrict__ lst,
    const int* __restrict__ flags, float* __restrict__ outw)
{
    __shared__ short As[2 * 128 * BK] __attribute__((aligned(16)));
    __shared__ short Bs[2 * 128 * BK] __attribute__((aligned(16)));
    if (blockIdx.z == 4) {
        const int bflat = blockIdx.y * gridDim.x + blockIdx.x;   // 0..255
#pragma unroll
        for (int u = 0; u < 8; ++u) {
            int idx = bflat * 4096 + u * 512 + threadIdx.x;      // over NN*NN/4
            int i  = idx >> 9;
            int j4 = (idx & 511) << 2;
            float4 wv = reinterpret_cast<const float4*>(w)[idx];
            float o[4] = {wv.x, wv.y, wv.z, wv.w};
            const int   rsi = flags[i];
            const float tsi = 10.0f - lst[i];
#pragma unroll
            for (int t = 0; t < 4; ++t) {
                int j = j4 + t;
                if (rsi | flags[j]) {
                    float dtm = tsi - (10.0f - lst[j]);
                    float dw = (dtm > 0.0f) ? (-0.015f * expf(-fabsf(dtm) / 25.0f))
                                            : ( 0.02f  * expf(-fabsf(dtm) / 15.0f));
                    o[t] += dw;
                }
                o[t] = fminf(1.0f, fmaxf(-1.0f, o[t]));
            }
            reinterpret_cast<float4*>(outw)[idx] = make_float4(o[0], o[1], o[2], o[3]);
        }
        return;
    }
    gemm_body(A, B, P, As, Bs);
}

// ---------------- combine 4 partials + epilogue (+ merged conv) ----------------
__device__ __forceinline__ float comb4(const short* p0, const short* p1,
                                       const short* p2, const short* p3,
                                       int idx, int t) {
    // caller loads vectors; helper unused — kept simple below
    return 0.0f;
}

// EPI 1 merged with conv(W2): y==1 blocks convert convsrc->convdst.
__global__ void comb1_mix(
    const short* __restrict__ p0, const short* __restrict__ p1,
    const short* __restrict__ p2, const short* __restrict__ p3,
    const float* __restrict__ bias,
    const float* __restrict__ mp,
    const float* __restrict__ n_in, const float* __restrict__ m_in,
    const float* __restrict__ h_in,
    short* __restrict__ out_v,
    float* __restrict__ out_n, float* __restrict__ out_m,
    float* __restrict__ out_h,
    int* __restrict__ flags,
    const float* __restrict__ convsrc, short* __restrict__ convdst)
{
    int idx = blockIdx.x * blockDim.x + threadIdx.x;   // over NN*NN/4
    if (blockIdx.y == 1) { conv_item(convsrc, convdst, idx); return; }
    int row = idx >> 9;
    int g   = idx & 511;
    s16x4 a = reinterpret_cast<const s16x4*>(p0)[idx];
    s16x4 b = reinterpret_cast<const s16x4*>(p1)[idx];
    s16x4 c = reinterpret_cast<const s16x4*>(p2)[idx];
    s16x4 d = reinterpret_cast<const s16x4*>(p3)[idx];
    float4 bi = reinterpret_cast<const float4*>(bias)[g];
    float pre[4] = { bf2f(a.x) + bf2f(b.x) + bf2f(c.x) + bf2f(d.x) + bi.x,
                     bf2f(a.y) + bf2f(b.y) + bf2f(c.y) + bf2f(d.y) + bi.y,
                     bf2f(a.z) + bf2f(b.z) + bf2f(c.z) + bf2f(d.z) + bi.z,
                     bf2f(a.w) + bf2f(b.w) + bf2f(c.w) + bf2f(d.w) + bi.w };
    float4 mp4 = reinterpret_cast<const float4*>(mp)[g];
    float4 n4  = reinterpret_cast<const float4*>(n_in)[g];
    float4 m4  = reinterpret_cast<const float4*>(m_in)[g];
    float4 h4  = reinterpret_cast<const float4*>(h_in)[g];
    float mpv[4] = {mp4.x, mp4.y, mp4.z, mp4.w};
    float nv[4]  = {n4.x, n4.y, n4.z, n4.w};
    float mv[4]  = {m4.x, m4.y, m4.z, m4.w};
    float hv[4]  = {h4.x, h4.y, h4.z, h4.w};
    s16x4 vb;
    float on[4], om[4], oh[4];
#pragma unroll
    for (int t = 0; t < 4; ++t) {
        float v = 0.5f * mpv[t] + sigmoidf_(pre[t]);
        if (v > 1.0f) { flags[row] = 1; v = 0.0f; }
        vb[t] = f2bf(v);
        float an = 0.01f * (v + 55.0f) / (1.0f - expf(-(v + 55.0f) / 10.0f));
        float bn = 0.125f * expf(-(v + 65.0f) / 80.0f);
        float am = 0.1f  * (v + 40.0f) / (1.0f - expf(-(v + 40.0f) / 10.0f));
        float bm = 4.0f  * expf(-(v + 65.0f) / 18.0f);
        float ah = 0.07f * expf(-(v + 65.0f) / 20.0f);
        float bh = 1.0f  / (1.0f + expf(-(v + 35.0f) / 10.0f));
        on[t] = nv[t] + 0.01f * (an * (1.0f - nv[t]) - bn * nv[t]);
        om[t] = mv[t] + 0.01f * (am * (1.0f - mv[t]) - bm * mv[t]);
        oh[t] = hv[t] + 0.01f * (ah * (1.0f - hv[t]) - bh * hv[t]);
    }
    reinterpret_cast<s16x4*>(out_v)[idx] = vb;
    reinterpret_cast<float4*>(out_n)[idx] = make_float4(on[0], on[1], on[2], on[3]);
    reinterpret_cast<float4*>(out_m)[idx] = make_float4(om[0], om[1], om[2], om[3]);
    reinterpret_cast<float4*>(out_h)[idx] = make_float4(oh[0], oh[1], oh[2], oh[3]);
}

// EPI 2 merged with conv(W3): y==1 blocks convert convsrc->convdst.
__global__ void comb2_mix(
    const short* __restrict__ p0, const short* __restrict__ p1,
    const short* __restrict__ p2, const short* __restrict__ p3,
    const float* __restrict__ bias,
    short* __restrict__ out_bf,
    const float* __restrict__ convsrc, short* __restrict__ convdst)
{
    int idx = blockIdx.x * blockDim.x + threadIdx.x;
    if (blockIdx.y == 1) { conv_item(convsrc, convdst, idx); return; }
    int g = idx & 511;
    s16x4 a = reinterpret_cast<const s16x4*>(p0)[idx];
    s16x4 b = reinterpret_cast<const s16x4*>(p1)[idx];
    s16x4 c = reinterpret_cast<const s16x4*>(p2)[idx];
    s16x4 d = reinterpret_cast<const s16x4*>(p3)[idx];
    float4 bi = reinterpret_cast<const float4*>(bias)[g];
    s16x4 o;
    o.x = f2bf(sigmoidf_(bf2f(a.x) + bf2f(b.x) + bf2f(c.x) + bf2f(d.x) + bi.x));
    o.y = f2bf(sigmoidf_(bf2f(a.y) + bf2f(b.y) + bf2f(c.y) + bf2f(d.y) + bi.y));
    o.z = f2bf(sigmoidf_(bf2f(a.z) + bf2f(b.z) + bf2f(c.z) + bf2f(d.z) + bi.z));
    o.w = f2bf(sigmoidf_(bf2f(a.w) + bf2f(b.w) + bf2f(c.w) + bf2f(d.w) + bi.w));
    reinterpret_cast<s16x4*>(out_bf)[idx] = o;
}

// EPI 3: f32 sigmoid
__global__ void combine3(
    const short* __restrict__ p0, const short* __restrict__ p1,
    const short* __restrict__ p2, const short* __restrict__ p3,
    const float* __restrict__ bias, float* __restrict__ out_f)
{
    int idx = blockIdx.x * blockDim.x + threadIdx.x;
    int g = idx & 511;
    s16x4 a = reinterpret_cast<const s16x4*>(p0)[idx];
    s16x4 b = reinterpret_cast<const s16x4*>(p1)[idx];
    s16x4 c = reinterpret_cast<const s16x4*>(p2)[idx];
    s16x4 d = reinterpret_cast<const s16x4*>(p3)[idx];
    float4 bi = reinterpret_cast<const float4*>(bias)[g];
    reinterpret_cast<float4*>(out_f)[idx] = make_float4(
        sigmoidf_(bf2f(a.x) + bf2f(b.x) + bf2f(c.x) + bf2f(d.x) + bi.x),
        sigmoidf_(bf2f(a.y) + bf2f(b.y) + bf2f(c.y) + bf2f(d.y) + bi.y),
        sigmoidf_(bf2f(a.z) + bf2f(b.z) + bf2f(c.z) + bf2f(d.z) + bi.z),
        sigmoidf_(bf2f(a.w) + bf2f(b.w) + bf2f(c.w) + bf2f(d.w) + bi.w));
}

extern "C" void kernel_launch(void* const* d_in, const int* in_sizes, int n_in,
                              void* d_out, int out_size, void* d_ws, size_t ws_size,
                              hipStream_t stream)
{
    const float* x   = (const float*)d_in[0];
    const float* W1  = (const float*)d_in[1];
    const float* b1  = (const float*)d_in[2];
    const float* W2  = (const float*)d_in[3];
    const float* b2  = (const float*)d_in[4];
    const float* W3  = (const float*)d_in[5];
    const float* b3  = (const float*)d_in[6];
    const float* wts = (const float*)d_in[7];
    const float* lst = (const float*)d_in[8];
    const float* mp  = (const float*)d_in[9];
    const float* nin = (const float*)d_in[10];
    const float* min_ = (const float*)d_in[11];
    const float* hin = (const float*)d_in[12];

    const size_t NSQ = (size_t)NN * NN;
    float* out    = (float*)d_out;          // [N,N] final MLP output
    float* out_w  = out + NSQ;              // new_weights
    float* out_n  = out + 2 * NSQ;
    float* out_m  = out + 3 * NSQ;
    float* out_h  = out + 4 * NSQ;

    // ws: S0 (xb->vb->w3b), S1 (w1b->w2b->h1b), P[4] partials, flags. 48 MB.
    short* S0 = (short*)d_ws;
    short* S1 = S0 + NSQ;
    short* P  = S1 + NSQ;
    int* flags = (int*)(P + 4 * NSQ);

    const int convBlocks = (int)(NSQ / 4 / 256);   // 4096 per array

    // 1: x->S0, W1->S1, zero flags
    conv2_kernel<<<dim3(convBlocks, 2), 256, 0, stream>>>(x, W1, S0, S1, flags);
    // 2: GEMM1 partials: x @ W1^T
    gemm_partial<<<dim3(NT, NT, 4), 512, 0, stream>>>(S0, S1, P);
    // 3: combine1 (v->S0, n/m/h, flags) + conv W2->S1
    comb1_mix<<<dim3(convBlocks, 2), 256, 0, stream>>>(
        P, P + NSQ, P + 2 * NSQ, P + 3 * NSQ, b1, mp, nin, min_, hin,
        S0, out_n, out_m, out_h, flags, W2, S1);
    // 4: GEMM2 partials (v @ W2^T) + STDP overlapped as z==4 slice
    gemm_stdp<<<dim3(NT, NT, 5), 512, 0, stream>>>(S0, S1, P, wts, lst, flags, out_w);
    // 5: combine2 (h1->S1) + conv W3->S0
    comb2_mix<<<dim3(convBlocks, 2), 256, 0, stream>>>(
        P, P + NSQ, P + 2 * NSQ, P + 3 * NSQ, b2, S1, W3, S0);
    // 6: GEMM3 partials: h1 @ W3^T
    gemm_partial<<<dim3(NT, NT, 4), 512, 0, stream>>>(S1, S0, P);
    // 7: combine3: out = sigmoid(.) -> f32
    combine3<<<convBlocks, 256, 0, stream>>>(
        P, P + NSQ, P + 2 * NSQ, P + 3 * NSQ, b3, out);
}

// Round 11
// 123.854 us; speedup vs baseline: 1.2526x; 1.2526x over previous
//
#include <hip/hip_runtime.h>
#include <hip/hip_bf16.h>
#include <math.h>

// SpikingNeuralNetwork: 3 chained bf16-MFMA GEMMs + elementwise epilogues.
// N = 2048. Round 11: r7 GEMM config exactly (split-K=2, 128x128 tile, BK=64
// double-buffered, 8 waves, 2 blocks/CU — best measured: 133.9 us) plus
// launch merges validated in r10: conv-W2 inside combine1's dispatch,
// conv-W3 inside combine2's, STDP as the z==2 slice of GEMM2's dispatch.
// 7 launches total.

#define NN 2048
#define BK 64
#define KHALF (NN / 2)
#define KTH (KHALF / BK)   // 16 K-tiles per half
#define NT (NN / 128)      // 16 tiles per dim

typedef __attribute__((ext_vector_type(8))) short bf16x8;
typedef __attribute__((ext_vector_type(4))) float f32x4;
typedef __attribute__((ext_vector_type(4))) short s16x4;

__device__ __forceinline__ short f2bf(float f) {
    union { float f; unsigned u; } a; a.f = f;
    unsigned r = a.u + 0x7FFFu + ((a.u >> 16) & 1u);   // RNE
    return (short)(r >> 16);
}

__device__ __forceinline__ float bf2f(short s) {
    union { unsigned u; float f; } a;
    a.u = ((unsigned)(unsigned short)s) << 16;
    return a.f;
}

__device__ __forceinline__ void gload16(const short* g, short* l) {
    __builtin_amdgcn_global_load_lds(
        (const __attribute__((address_space(1))) unsigned int*)g,
        (__attribute__((address_space(3))) unsigned int*)l, 16, 0, 0);
}

__device__ __forceinline__ float sigmoidf_(float x) {
    return 1.0f / (1.0f + expf(-x));
}

__device__ __forceinline__ void conv_item(const float* __restrict__ src,
                                          short* __restrict__ dst, int i) {
    float4 v = reinterpret_cast<const float4*>(src)[i];
    s16x4 o;
    o.x = f2bf(v.x); o.y = f2bf(v.y); o.z = f2bf(v.z); o.w = f2bf(v.w);
    reinterpret_cast<s16x4*>(dst)[i] = o;
}

// ---------------- conv x, W1 (+ zero flags) ----------------
__global__ void conv2_kernel(const float* __restrict__ s0, const float* __restrict__ s1,
                             short* __restrict__ d0, short* __restrict__ d1,
                             int* __restrict__ flags)
{
    int i = blockIdx.x * blockDim.x + threadIdx.x;   // over NN*NN/4
    if (blockIdx.y == 0) {
        conv_item(s0, d0, i);
        if (blockIdx.x < NN / 256)
            flags[blockIdx.x * blockDim.x + threadIdx.x] = 0;
    } else {
        conv_item(s1, d1, i);
    }
}

// ---------------- split-K=2 GEMM body (r7 config) ----------------
// C_z = A[:, z*1024 +: 1024] @ B^T slice. 128x128 tile, 8 waves (2x4) of
// 64x32, BK=64 double-buffered (64 KB LDS), XOR-swizzled. 2 blocks/CU.
__device__ __forceinline__ void gemm_body(
    const short* __restrict__ A, const short* __restrict__ B,
    short* __restrict__ P, short (*As)[128 * BK], short (*Bs)[128 * BK])
{
    const int tid  = threadIdx.x;
    const int lane = tid & 63;
    const int wid  = tid >> 6;          // 0..7
    const int row0 = blockIdx.y * 128;
    const int col0 = blockIdx.x * 128;
    const int kbase = blockIdx.z * KHALF;
    const int wm   = (wid >> 2) * 64;   // wave sub-tile origin in M (0/64)
    const int wn   = (wid & 3) * 32;    // in N (0/32/64/96)
    const int lrow = lane & 15;
    const int lk16 = (lane >> 4) << 3;  // 0/8/16/24

    f32x4 acc[4][2] = {};

    // LDS dest linear (global_load_lds requirement); global source inverse-
    // swizzled so a swizzled ds_read returns linear fragments (rule #21).
    auto stage = [&](int buf, int k0) {
#pragma unroll
        for (int s = 0; s < 2; ++s) {
            int c = tid + s * 512;                       // chunk id 0..1023
            int r = c >> 3;                              // row in tile
            int ksrc = ((c & 7) ^ (r & 7)) << 3;         // swizzled k (bf16 elems)
            gload16(A + (size_t)(row0 + r) * NN + k0 + ksrc, &As[buf][c * 8]);
            gload16(B + (size_t)(col0 + r) * NN + k0 + ksrc, &Bs[buf][c * 8]);
        }
    };

    auto compute = [&](int buf) {
        bf16x8 af[4][2], bfv[2][2];
#pragma unroll
        for (int i = 0; i < 4; ++i) {
            const int row = wm + i * 16 + lrow;
#pragma unroll
            for (int kk = 0; kk < 2; ++kk) {
                const int ke = (lk16 + kk * 32) ^ ((row & 7) << 3);
                af[i][kk] = *reinterpret_cast<const bf16x8*>(&As[buf][row * BK + ke]);
            }
        }
#pragma unroll
        for (int j = 0; j < 2; ++j) {
            const int row = wn + j * 16 + lrow;
#pragma unroll
            for (int kk = 0; kk < 2; ++kk) {
                const int ke = (lk16 + kk * 32) ^ ((row & 7) << 3);
                bfv[j][kk] = *reinterpret_cast<const bf16x8*>(&Bs[buf][row * BK + ke]);
            }
        }
#pragma unroll
        for (int kk = 0; kk < 2; ++kk)
#pragma unroll
            for (int i = 0; i < 4; ++i)
#pragma unroll
                for (int j = 0; j < 2; ++j)
                    acc[i][j] = __builtin_amdgcn_mfma_f32_16x16x32_bf16(
                        af[i][kk], bfv[j][kk], acc[i][j], 0, 0, 0);
    };

    // 2-phase pipeline: STAGE(next) before compute(cur); one vmcnt(0)+barrier
    // per iteration (__syncthreads). 2 blocks/CU fill each other's stalls.
    stage(0, kbase);
    __syncthreads();
    int cur = 0;
    for (int t = 0; t < KTH - 1; ++t) {
        stage(cur ^ 1, kbase + (t + 1) * BK);
        compute(cur);
        __syncthreads();
        cur ^= 1;
    }
    compute(cur);

    // write bf16 partial — C/D layout: col = lane&15, row = (lane>>4)*4 + reg
    short* outp = P + (size_t)blockIdx.z * NN * NN;
#pragma unroll
    for (int i = 0; i < 4; ++i) {
#pragma unroll
        for (int j = 0; j < 2; ++j) {
            const int gcol = col0 + wn + j * 16 + lrow;
#pragma unroll
            for (int r = 0; r < 4; ++r) {
                const int grow = row0 + wm + i * 16 + ((lane >> 4) << 2) + r;
                outp[(size_t)grow * NN + gcol] = f2bf(acc[i][j][r]);
            }
        }
    }
}

__global__ __launch_bounds__(512) void gemm_partial(
    const short* __restrict__ A, const short* __restrict__ B,
    short* __restrict__ P)
{
    __shared__ short As[2][128 * BK] __attribute__((aligned(16)));
    __shared__ short Bs[2][128 * BK] __attribute__((aligned(16)));
    gemm_body(A, B, P, As, Bs);
}

// GEMM2 + STDP fused dispatch: grid (16,16,3); z==2 blocks run STDP
// (overlaps the GEMM; STDP only needs flags, finalized by combine1).
__global__ __launch_bounds__(512) void gemm_stdp(
    const short* __restrict__ A, const short* __restrict__ B,
    short* __restrict__ P,
    const float* __restrict__ w, const float* __restrict__ lst,
    const int* __restrict__ flags, float* __restrict__ outw)
{
    __shared__ short As[2][128 * BK] __attribute__((aligned(16)));
    __shared__ short Bs[2][128 * BK] __attribute__((aligned(16)));
    if (blockIdx.z == 2) {
        const int bflat = blockIdx.y * gridDim.x + blockIdx.x;   // 0..255
#pragma unroll
        for (int u = 0; u < 8; ++u) {
            int idx = bflat * 4096 + u * 512 + threadIdx.x;      // over NN*NN/4
            int i  = idx >> 9;
            int j4 = (idx & 511) << 2;
            float4 wv = reinterpret_cast<const float4*>(w)[idx];
            float o[4] = {wv.x, wv.y, wv.z, wv.w};
            const int   rsi = flags[i];
            const float tsi = 10.0f - lst[i];
#pragma unroll
            for (int t = 0; t < 4; ++t) {
                int j = j4 + t;
                if (rsi | flags[j]) {
                    float dtm = tsi - (10.0f - lst[j]);
                    float dw = (dtm > 0.0f) ? (-0.015f * expf(-fabsf(dtm) / 25.0f))
                                            : ( 0.02f  * expf(-fabsf(dtm) / 15.0f));
                    o[t] += dw;
                }
                o[t] = fminf(1.0f, fmaxf(-1.0f, o[t]));
            }
            reinterpret_cast<float4*>(outw)[idx] = make_float4(o[0], o[1], o[2], o[3]);
        }
        return;
    }
    gemm_body(A, B, P, As, Bs);
}

// ---------------- combine1 (v/HH/spike) + merged conv(W2) ----------------
__global__ void comb1_mix(
    const short* __restrict__ p0, const short* __restrict__ p1,
    const float* __restrict__ bias,
    const float* __restrict__ mp,
    const float* __restrict__ n_in, const float* __restrict__ m_in,
    const float* __restrict__ h_in,
    short* __restrict__ out_v,
    float* __restrict__ out_n, float* __restrict__ out_m,
    float* __restrict__ out_h,
    int* __restrict__ flags,
    const float* __restrict__ convsrc, short* __restrict__ convdst)
{
    int idx = blockIdx.x * blockDim.x + threadIdx.x;   // over NN*NN/4
    if (blockIdx.y == 1) { conv_item(convsrc, convdst, idx); return; }
    int row = idx >> 9;
    int g   = idx & 511;
    s16x4 a = reinterpret_cast<const s16x4*>(p0)[idx];
    s16x4 b = reinterpret_cast<const s16x4*>(p1)[idx];
    float4 bi = reinterpret_cast<const float4*>(bias)[g];
    float pre[4] = { bf2f(a.x) + bf2f(b.x) + bi.x,
                     bf2f(a.y) + bf2f(b.y) + bi.y,
                     bf2f(a.z) + bf2f(b.z) + bi.z,
                     bf2f(a.w) + bf2f(b.w) + bi.w };
    float4 mp4 = reinterpret_cast<const float4*>(mp)[g];
    float4 n4  = reinterpret_cast<const float4*>(n_in)[g];
    float4 m4  = reinterpret_cast<const float4*>(m_in)[g];
    float4 h4  = reinterpret_cast<const float4*>(h_in)[g];
    float mpv[4] = {mp4.x, mp4.y, mp4.z, mp4.w};
    float nv[4]  = {n4.x, n4.y, n4.z, n4.w};
    float mv[4]  = {m4.x, m4.y, m4.z, m4.w};
    float hv[4]  = {h4.x, h4.y, h4.z, h4.w};
    s16x4 vb;
    float on[4], om[4], oh[4];
#pragma unroll
    for (int t = 0; t < 4; ++t) {
        float v = 0.5f * mpv[t] + sigmoidf_(pre[t]);
        if (v > 1.0f) { flags[row] = 1; v = 0.0f; }
        vb[t] = f2bf(v);
        float an = 0.01f * (v + 55.0f) / (1.0f - expf(-(v + 55.0f) / 10.0f));
        float bn = 0.125f * expf(-(v + 65.0f) / 80.0f);
        float am = 0.1f  * (v + 40.0f) / (1.0f - expf(-(v + 40.0f) / 10.0f));
        float bm = 4.0f  * expf(-(v + 65.0f) / 18.0f);
        float ah = 0.07f * expf(-(v + 65.0f) / 20.0f);
        float bh = 1.0f  / (1.0f + expf(-(v + 35.0f) / 10.0f));
        on[t] = nv[t] + 0.01f * (an * (1.0f - nv[t]) - bn * nv[t]);
        om[t] = mv[t] + 0.01f * (am * (1.0f - mv[t]) - bm * mv[t]);
        oh[t] = hv[t] + 0.01f * (ah * (1.0f - hv[t]) - bh * hv[t]);
    }
    reinterpret_cast<s16x4*>(out_v)[idx] = vb;
    reinterpret_cast<float4*>(out_n)[idx] = make_float4(on[0], on[1], on[2], on[3]);
    reinterpret_cast<float4*>(out_m)[idx] = make_float4(om[0], om[1], om[2], om[3]);
    reinterpret_cast<float4*>(out_h)[idx] = make_float4(oh[0], oh[1], oh[2], oh[3]);
}

// ---------------- combine2 (bf16 sigmoid) + merged conv(W3) ----------------
__global__ void comb2_mix(
    const short* __restrict__ p0, const short* __restrict__ p1,
    const float* __restrict__ bias,
    short* __restrict__ out_bf,
    const float* __restrict__ convsrc, short* __restrict__ convdst)
{
    int idx = blockIdx.x * blockDim.x + threadIdx.x;
    if (blockIdx.y == 1) { conv_item(convsrc, convdst, idx); return; }
    int g = idx & 511;
    s16x4 a = reinterpret_cast<const s16x4*>(p0)[idx];
    s16x4 b = reinterpret_cast<const s16x4*>(p1)[idx];
    float4 bi = reinterpret_cast<const float4*>(bias)[g];
    s16x4 o;
    o.x = f2bf(sigmoidf_(bf2f(a.x) + bf2f(b.x) + bi.x));
    o.y = f2bf(sigmoidf_(bf2f(a.y) + bf2f(b.y) + bi.y));
    o.z = f2bf(sigmoidf_(bf2f(a.z) + bf2f(b.z) + bi.z));
    o.w = f2bf(sigmoidf_(bf2f(a.w) + bf2f(b.w) + bi.w));
    reinterpret_cast<s16x4*>(out_bf)[idx] = o;
}

// ---------------- combine3 (f32 sigmoid) ----------------
__global__ void combine3(
    const short* __restrict__ p0, const short* __restrict__ p1,
    const float* __restrict__ bias, float* __restrict__ out_f)
{
    int idx = blockIdx.x * blockDim.x + threadIdx.x;
    int g = idx & 511;
    s16x4 a = reinterpret_cast<const s16x4*>(p0)[idx];
    s16x4 b = reinterpret_cast<const s16x4*>(p1)[idx];
    float4 bi = reinterpret_cast<const float4*>(bias)[g];
    reinterpret_cast<float4*>(out_f)[idx] = make_float4(
        sigmoidf_(bf2f(a.x) + bf2f(b.x) + bi.x),
        sigmoidf_(bf2f(a.y) + bf2f(b.y) + bi.y),
        sigmoidf_(bf2f(a.z) + bf2f(b.z) + bi.z),
        sigmoidf_(bf2f(a.w) + bf2f(b.w) + bi.w));
}

extern "C" void kernel_launch(void* const* d_in, const int* in_sizes, int n_in,
                              void* d_out, int out_size, void* d_ws, size_t ws_size,
                              hipStream_t stream)
{
    const float* x   = (const float*)d_in[0];
    const float* W1  = (const float*)d_in[1];
    const float* b1  = (const float*)d_in[2];
    const float* W2  = (const float*)d_in[3];
    const float* b2  = (const float*)d_in[4];
    const float* W3  = (const float*)d_in[5];
    const float* b3  = (const float*)d_in[6];
    const float* wts = (const float*)d_in[7];
    const float* lst = (const float*)d_in[8];
    const float* mp  = (const float*)d_in[9];
    const float* nin = (const float*)d_in[10];
    const float* min_ = (const float*)d_in[11];
    const float* hin = (const float*)d_in[12];

    const size_t NSQ = (size_t)NN * NN;
    float* out    = (float*)d_out;          // [N,N] final MLP output
    float* out_w  = out + NSQ;              // new_weights
    float* out_n  = out + 2 * NSQ;
    float* out_m  = out + 3 * NSQ;
    float* out_h  = out + 4 * NSQ;

    // ws layout (48 MB + flags): R1 xb->w3b; R2 w1b->h1b; R3 vb; R4 w2b;
    // P = 2x8MB bf16 partials.
    short* R1 = (short*)d_ws;
    short* R2 = R1 + NSQ;
    short* R3 = R2 + NSQ;
    short* R4 = R3 + NSQ;
    short* P  = R4 + NSQ;
    int* flags = (int*)(P + 2 * NSQ);

    const int convBlocks = (int)(NSQ / 4 / 256);   // 4096 per array

    // 1: x->R1, W1->R2 (+ zero flags)
    conv2_kernel<<<dim3(convBlocks, 2), 256, 0, stream>>>(x, W1, R1, R2, flags);
    // 2: GEMM1 partials: x @ W1^T
    gemm_partial<<<dim3(NT, NT, 2), 512, 0, stream>>>(R1, R2, P);
    // 3: combine1 (v->R3, n/m/h, flags) + conv W2->R4
    comb1_mix<<<dim3(convBlocks, 2), 256, 0, stream>>>(
        P, P + NSQ, b1, mp, nin, min_, hin,
        R3, out_n, out_m, out_h, flags, W2, R4);
    // 4: GEMM2 partials (v @ W2^T) + STDP overlapped as z==2 slice
    gemm_stdp<<<dim3(NT, NT, 3), 512, 0, stream>>>(R3, R4, P, wts, lst, flags, out_w);
    // 5: combine2 (h1->R2) + conv W3->R1
    comb2_mix<<<dim3(convBlocks, 2), 256, 0, stream>>>(
        P, P + NSQ, b2, R2, W3, R1);
    // 6: GEMM3 partials: h1 @ W3^T
    gemm_partial<<<dim3(NT, NT, 2), 512, 0, stream>>>(R2, R1, P);
    // 7: combine3: out = sigmoid(.) -> f32
    combine3<<<convBlocks, 256, 0, stream>>>(P, P + NSQ, b3, out);
}